// Round 20
// baseline (296.356 us; speedup 1.0000x reference)
//
#include <hip/hip_runtime.h>
#include <hip/hip_bf16.h>

#define N_TOK 4096
#define HD    2048
#define NE    8

#define BM 128
#define BN 256
#define BK 32
#define NKS (HD/BK)                 /* 64 K-steps */
#define MAXROWS (N_TOK*2 + NE*BM)   /* 9216 */
#define TMAX (MAXROWS/BM)           /* 72 m-tiles */
#define NNT  (HD/BN)                /* 8 n-tiles */
#define NWG  (TMAX*NNT)             /* 576 blocks */
#define TSZ  ((BM+BN)*BK*2)         /* 24 KiB per K-tile buffer */

#define NCOPY 64                    /* privatized counter copies */
#define NCVT1 2048                  /* W1-convert-role blocks (256 thr kernel) */
#define NGATE (N_TOK/4)             /* 1024 gate-role blocks */
#define NXCV  (N_TOK*HD/2048)       /* 4096 x-convert-role blocks */
#define NCVT2 2048                  /* W2-convert-role blocks (in gemm1 launch) */

typedef __attribute__((ext_vector_type(4))) float f32x4;
typedef __attribute__((ext_vector_type(8))) short short8;
typedef __attribute__((ext_vector_type(8))) unsigned short ushort8;

typedef unsigned short u16;
typedef unsigned int   u32;

// meta int layout: [0..511] cnt[64][8]   [1024..1031] tot[8] (written by fill)

__device__ __forceinline__ float bf2f(u16 u) {
  union { u32 i; float f; } c; c.i = ((u32)u) << 16; return c.f;
}
__device__ __forceinline__ u16 f2bf(float f) {  // round-to-nearest-even
  u32 x = __float_as_uint(f);
  u32 r = (x + 0x7fffu + ((x >> 16) & 1u)) >> 16;
  return (u16)r;
}

__device__ __forceinline__ void gload_lds16(const void* gsrc, void* ldst) {
  __builtin_amdgcn_global_load_lds(
      (const __attribute__((address_space(1))) u32*)gsrc,
      (__attribute__((address_space(3))) u32*)ldst, 16, 0, 0);
}

// ---------------- fused: W1 convert+transpose (b<2048) || gate (2048..3071) ||
//                  x fp32->bf16 (3072..7167) — independent roles
// convert swizzle v5 (verified, 0 conflicts): slot XOR on (r>>3)&7.
__global__ __launch_bounds__(256) void convert_gate_kernel(
    const float* __restrict__ W1, u16* __restrict__ W1T,
    const float* __restrict__ x, const float* __restrict__ gW,
    const float* __restrict__ gb, float* __restrict__ gate_out,
    int* __restrict__ cnt, int* __restrict__ picks, float* __restrict__ wts,
    u16* __restrict__ Xbf) {
  __shared__ float smem[NE*HD];         // 64 KiB; convert & gate roles use it
  int b = blockIdx.x;
  int t = threadIdx.x;

  if (b >= NCVT1 + NGATE) {
    // ---- x-convert role: fp32 -> bf16, token order preserved (no LDS)
    size_t base = (size_t)(b - NCVT1 - NGATE) * 2048 + (size_t)t * 8;
    f32x4 a = *reinterpret_cast<const f32x4*>(x + base);
    f32x4 c = *reinterpret_cast<const f32x4*>(x + base + 4);
    ushort8 v;
    #pragma unroll
    for (int j = 0; j < 4; ++j) { v[j] = f2bf(a[j]); v[4+j] = f2bf(c[j]); }
    *reinterpret_cast<ushort8*>(Xbf + base) = v;
  } else if (b < NCVT1) {
    // ---- W1 convert role: W1[e][k][n] f32 -> W1T[e][n][k] bf16
    f32x4* tile4 = reinterpret_cast<f32x4*>(smem);
    int bx = b & 7, by = (b >> 3) & 31, e = b >> 8;   // 8 x 32 x 8
    size_t ebase = (size_t)e * HD * HD;
    int n0 = bx * 256;
    int k0 = by * 64;
    int l = t & 63, w = t >> 6;
    #pragma unroll
    for (int i = 0; i < 16; ++i) {
      int r = i*4 + w;
      f32x4 v = *reinterpret_cast<const f32x4*>(W1 + ebase + (size_t)(k0 + r) * HD + n0 + l*4);
      tile4[r*64 + (l ^ ((r >> 3) & 7))] = v;   // b128 write, minimal banks
    }
    __syncthreads();
    #pragma unroll
    for (int i = 0; i < 8; ++i) {
      int np = i*32 + (t >> 3);           // out row (n')
      int kc = (t & 7) * 8;               // out col base (k)
      int c4 = np >> 2, inner = np & 3;
      ushort8 v;
      #pragma unroll
      for (int j = 0; j < 8; ++j) {
        int k = kc + j;
        v[j] = f2bf(smem[(k*64 + (c4 ^ ((k >> 3) & 7)))*4 + inner]);  // 2-way
      }
      *reinterpret_cast<ushort8*>(W1T + ebase + (size_t)(n0 + np) * HD + k0 + kc) = v;
    }
  } else {
    // ---- gate role: gW staged in LDS; softmax -> top2 -> privatized atomics
    float* gwl = smem;                    // 64 KiB
    int gbk = b - NCVT1;                  // 0..1023
    {
      const f32x4* g4 = reinterpret_cast<const f32x4*>(gW);
      f32x4* l4 = reinterpret_cast<f32x4*>(gwl);
      #pragma unroll
      for (int i = 0; i < 16; ++i) l4[i*256 + t] = g4[i*256 + t];
    }
    __syncthreads();
    int wid = (gbk << 2) + (t >> 6);      // token
    int lane = t & 63;
    int copy = gbk & (NCOPY-1);
    const float* xr = x + (size_t)wid * HD;
    float s[NE] = {};
    for (int k = 0; k < HD; k += 256) {   // 8 iters, f32x4 per lane
      f32x4 xv = *reinterpret_cast<const f32x4*>(xr + k + lane*4);
      #pragma unroll
      for (int e = 0; e < NE; ++e) {
        f32x4 wv = *reinterpret_cast<const f32x4*>(&gwl[e*HD + k + lane*4]);
        s[e] += xv[0]*wv[0] + xv[1]*wv[1] + xv[2]*wv[2] + xv[3]*wv[3];
      }
    }
    #pragma unroll
    for (int e = 0; e < NE; ++e) {
      float v = s[e];
      #pragma unroll
      for (int off = 32; off > 0; off >>= 1) v += __shfl_xor(v, off);
      s[e] = v + gb[e];
    }
    float mx = s[0];
    #pragma unroll
    for (int e = 1; e < NE; ++e) mx = fmaxf(mx, s[e]);
    float sum = 0.f;
    #pragma unroll
    for (int e = 0; e < NE; ++e) { s[e] = expf(s[e] - mx); sum += s[e]; }
    float inv = 1.f / sum;
    #pragma unroll
    for (int e = 0; e < NE; ++e) s[e] *= inv;
    int e0 = 0; float v0 = s[0];
    #pragma unroll
    for (int e = 1; e < NE; ++e) if (s[e] > v0) { v0 = s[e]; e0 = e; }
    int e1 = -1; float v1 = -1.f;
    #pragma unroll
    for (int e = 0; e < NE; ++e) if (e != e0 && s[e] > v1) { v1 = s[e]; e1 = e; }
    if (lane == 0) {
      #pragma unroll
      for (int e = 0; e < NE; ++e) gate_out[(size_t)wid*NE + e] = s[e];
      int p0 = atomicAdd(&cnt[copy*8 + e0], 1);
      int p1 = atomicAdd(&cnt[copy*8 + e1], 1);
      picks[wid*2]   = (p0 << 9) | (copy << 3) | e0;
      picks[wid*2+1] = (p1 << 9) | (copy << 3) | e1;
      wts[wid*2]   = v0;
      wts[wid*2+1] = v1;
    }
  }
}

// ---------------- fill: token picks -> padded row slots + row->token map.
// Computes prefix directly from cnt (thread-uniform scalar loads, L1-hot);
// block 0 threads 0..7 also publish per-expert totals tot[e] for the gemms.
__global__ void fill_kernel(const int* __restrict__ picks, int* __restrict__ meta,
                            int* __restrict__ slot, int* __restrict__ rowTok) {
  if (blockIdx.x == 0 && threadIdx.x < NE) {
    int e = threadIdx.x, run = 0;
    for (int cc = 0; cc < NCOPY; ++cc) run += meta[cc*8 + e];
    meta[1024 + e] = run;
  }
  int i = blockIdx.x * 256 + threadIdx.x;
  if (i >= N_TOK*2) return;
  int p = picks[i];
  int e = p & 7, c = (p >> 3) & (NCOPY-1), pos = p >> 9;
  int base = 0;
  #pragma unroll
  for (int ee = 0; ee < NE; ++ee) {
    if (ee < e) {
      int tt = 0;
      for (int cc = 0; cc < NCOPY; ++cc) tt += meta[cc*8 + ee];
      base += ((tt + BM - 1) >> 7) << 7;
    }
  }
  int cpfx = 0;
  for (int cc = 0; cc < c; ++cc) cpfx += meta[cc*8 + e];
  int row = base + cpfx + pos;
  slot[i] = row;
  rowTok[row] = i >> 1;
}

// ---------------- grouped GEMM core (512 thr, 128x256, BK=32, 3-buffer
// counted-vmcnt, 72 KiB LDS). IND: A rows via rowTok indirection.
__device__ __forceinline__ void compute_ktile(
    const char* ldsA, const char* ldsB, f32x4 (&acc)[4][4],
    int wr, int wc, int l15, int lhi) {
  short8 af[4], bfr[4];
  #pragma unroll
  for (int m = 0; m < 4; ++m) {
    int r = wr*64 + m*16 + l15;
    int c = lhi ^ ((r >> 1) & 3);       // swizzled read: worst 2-way (free)
    af[m] = *reinterpret_cast<const short8*>(ldsA + r*64 + c*16);
  }
  #pragma unroll
  for (int n = 0; n < 4; ++n) {
    int r = wc*64 + n*16 + l15;
    int c = lhi ^ ((r >> 1) & 3);
    bfr[n] = *reinterpret_cast<const short8*>(ldsB + r*64 + c*16);
  }
  #pragma unroll
  for (int m = 0; m < 4; ++m)
    #pragma unroll
    for (int n = 0; n < 4; ++n)
      acc[m][n] = __builtin_amdgcn_mfma_f32_16x16x32_bf16(af[m], bfr[n], acc[m][n], 0, 0, 0);
}

template<bool RELU, bool IND>
__device__ __forceinline__ void gemm_role(
    char* lds, int bid,
    const u16* __restrict__ A, const u16* __restrict__ WT,
    const float* __restrict__ bias, u16* __restrict__ Out,
    const int* __restrict__ tot, const int* __restrict__ rowTok) {
  // bijective XCD swizzle (m204): NWG % 8 == 0, chunk = NWG/8 = 72
  int wg = (bid & 7) * (NWG/8) + (bid >> 3);
  int t  = wg >> 3;          // m-tile index (0..71)
  int nt = wg & 7;           // n-tile index (0..7)
  // inline prefix over padded expert counts
  int tiles = 0, rows = 0, e = 0, tstart = 0, rbase = 0;
  #pragma unroll
  for (int i = 0; i < NE; ++i) {
    int tl = (tot[i] + BM - 1) >> 7;
    if (t >= tiles && t < tiles + tl) { e = i; tstart = tiles; rbase = rows; }
    tiles += tl; rows += tl << 7;
  }
  if (t >= tiles) return;
  int rowBase = rbase + (t - tstart) * BM;

  const u16* Bp = WT + ((size_t)e * HD + (size_t)nt * BN) * HD;

  int tid = threadIdx.x;
  int lane = tid & 63;
  int wv = tid >> 6;           // 0..7
  int wr = wv >> 2, wc = wv & 3;
  int l15 = lane & 15, lhi = lane >> 4;

  // hoisted per-thread staging sources (K-invariant row map)
  int aR = tid >> 2;
  int aC = (tid & 3) ^ ((aR >> 1) & 3);
  const u16* Asrc;
  if (IND) {
    int tk = rowTok[rowBase + aR];
    if (tk < 0) tk = 0;                  // pad row: finite garbage, never combined
    Asrc = A + (size_t)tk * HD + aC*8;
  } else {
    Asrc = A + (size_t)(rowBase + aR) * HD + aC*8;
  }
  int b1R = 128 + aR;
  int b1C = (tid & 3) ^ ((b1R >> 1) & 3);
  const u16* Bsrc0 = Bp + (size_t)aR * HD + aC*8;       // rows 0..127
  const u16* Bsrc1 = Bp + (size_t)b1R * HD + b1C*8;     // rows 128..255
  int ldsAoff = tid*16;
  int ldsB0off = BM*BK*2 + tid*16;
  int ldsB1off = BM*BK*2 + (512 + tid)*16;

  f32x4 acc[4][4] = {};

  // prologue: stage K-tiles 0 and 1
  gload_lds16(Asrc,       lds + ldsAoff);
  gload_lds16(Bsrc0,      lds + ldsB0off);
  gload_lds16(Bsrc1,      lds + ldsB1off);
  gload_lds16(Asrc  + BK, lds + TSZ + ldsAoff);
  gload_lds16(Bsrc0 + BK, lds + TSZ + ldsB0off);
  gload_lds16(Bsrc1 + BK, lds + TSZ + ldsB1off);

  int rd = 0;   // buffer holding K-tile ks (== ks % 3)
  for (int ks = 0; ks < NKS - 2; ++ks) {
    // own stage(ks) retired; stage(ks+1)'s 3 loads may stay in flight
    asm volatile("s_waitcnt vmcnt(3)" ::: "memory");
    // all waves: stage(ks) visible; all finished compute(ks-1)
    __builtin_amdgcn_s_barrier();
    int wi = rd + 2; if (wi >= 3) wi -= 3;
    // safe: buf[wi] last read at compute(ks-1), barrier-separated
    int koff = (ks+2)*BK;
    gload_lds16(Asrc  + koff, lds + wi*TSZ + ldsAoff);
    gload_lds16(Bsrc0 + koff, lds + wi*TSZ + ldsB0off);
    gload_lds16(Bsrc1 + koff, lds + wi*TSZ + ldsB1off);
    __builtin_amdgcn_sched_barrier(0);  // keep stage-issue before compute
    compute_ktile(lds + rd*TSZ, lds + rd*TSZ + BM*BK*2, acc, wr, wc, l15, lhi);
    if (++rd == 3) rd = 0;
  }
  // ks = NKS-2
  asm volatile("s_waitcnt vmcnt(3)" ::: "memory");
  __builtin_amdgcn_s_barrier();
  compute_ktile(lds + rd*TSZ, lds + rd*TSZ + BM*BK*2, acc, wr, wc, l15, lhi);
  if (++rd == 3) rd = 0;
  // ks = NKS-1: full drain
  asm volatile("s_waitcnt vmcnt(0)" ::: "memory");
  __builtin_amdgcn_s_barrier();
  compute_ktile(lds + rd*TSZ, lds + rd*TSZ + BM*BK*2, acc, wr, wc, l15, lhi);

  int orow = rowBase + wr*64;
  int ocol = nt*BN + wc*64;
  const float* bp = bias + (size_t)e * HD + ocol;
  #pragma unroll
  for (int n = 0; n < 4; ++n) {
    float bv = bp[n*16 + l15];
    #pragma unroll
    for (int m = 0; m < 4; ++m) {
      #pragma unroll
      for (int j = 0; j < 4; ++j) {
        float v = acc[m][n][j] + bv;
        if (RELU) v = fmaxf(v, 0.f);
        Out[(size_t)(orow + m*16 + lhi*4 + j) * HD + (ocol + n*16 + l15)] = f2bf(v);
      }
    }
  }
}

// ---------------- gemm1 fused with W2 convert role (independent blocks):
// blocks [0, NWG) run gemm1 (Xbf @ W1T -> Hbuf); blocks [NWG, NWG+NCVT2)
// convert W2 f32 -> W2T bf16 (consumed by the NEXT launch, gemm2).
__global__ __launch_bounds__(512, 4) void gemm1_convw2_kernel(
    const u16* __restrict__ A, const u16* __restrict__ WT,
    const float* __restrict__ bias, u16* __restrict__ Out,
    const int* __restrict__ tot, const int* __restrict__ rowTok,
    const float* __restrict__ W2, u16* __restrict__ W2T) {
  __shared__ char lds[3*TSZ];  // 72 KiB (convert role uses first 64 KiB)
  int bid = blockIdx.x;
  if (bid < NWG) {
    gemm_role<true, true>(lds, bid, A, WT, bias, Out, tot, rowTok);
  } else {
    // ---- W2 convert role, 512 threads: 64(k) x 256(n) tile, v5 swizzle
    float* smem = reinterpret_cast<float*>(lds);
    f32x4* tile4 = reinterpret_cast<f32x4*>(lds);
    int b2 = bid - NWG;                  // 0..2047
    int bx = b2 & 7, by = (b2 >> 3) & 31, e = b2 >> 8;  // 8 x 32 x 8
    size_t ebase = (size_t)e * HD * HD;
    int n0 = bx * 256;
    int k0 = by * 64;
    int t = threadIdx.x;
    int l = t & 63, w = t >> 6;          // w in 0..7
    #pragma unroll
    for (int i = 0; i < 8; ++i) {
      int r = i*8 + w;
      f32x4 v = *reinterpret_cast<const f32x4*>(W2 + ebase + (size_t)(k0 + r) * HD + n0 + l*4);
      tile4[r*64 + (l ^ ((r >> 3) & 7))] = v;
    }
    __syncthreads();
    #pragma unroll
    for (int i = 0; i < 4; ++i) {
      int np = i*64 + (t >> 3);           // out row (n'), 0..255
      int kc = (t & 7) * 8;               // out col base (k)
      int c4 = np >> 2, inner = np & 3;
      ushort8 v;
      #pragma unroll
      for (int j = 0; j < 8; ++j) {
        int k = kc + j;
        v[j] = f2bf(smem[(k*64 + (c4 ^ ((k >> 3) & 7)))*4 + inner]);
      }
      *reinterpret_cast<ushort8*>(W2T + ebase + (size_t)(n0 + np) * HD + k0 + kc) = v;
    }
  }
}

// ---------------- gemm2 (plain)
template<bool RELU, bool IND>
__global__ __launch_bounds__(512, 4) void moe_gemm_kernel(
    const u16* __restrict__ A, const u16* __restrict__ WT,
    const float* __restrict__ bias, u16* __restrict__ Out,
    const int* __restrict__ tot, const int* __restrict__ rowTok) {
  __shared__ char lds[3*TSZ];
  gemm_role<RELU, IND>(lds, blockIdx.x, A, WT, bias, Out, tot, rowTok);
}

// ---------------- combine: out[n] = w0*Y[slot0] + w1*Y[slot1]
__global__ __launch_bounds__(256) void combine_kernel(
    const u16* __restrict__ Y, const int* __restrict__ slot,
    const float* __restrict__ wts, float* __restrict__ out) {
  int n = blockIdx.x;
  int r0 = slot[n*2], r1 = slot[n*2+1];
  float w0 = wts[n*2], w1 = wts[n*2+1];
  int c = threadIdx.x * 8;
  ushort8 y0 = *reinterpret_cast<const ushort8*>(Y + (size_t)r0*HD + c);
  ushort8 y1 = *reinterpret_cast<const ushort8*>(Y + (size_t)r1*HD + c);
  f32x4 o0, o1;
  #pragma unroll
  for (int j = 0; j < 4; ++j) {
    o0[j] = w0*bf2f(y0[j])   + w1*bf2f(y1[j]);
    o1[j] = w0*bf2f(y0[4+j]) + w1*bf2f(y1[4+j]);
  }
  f32x4* dst = reinterpret_cast<f32x4*>(out + (size_t)n*HD + c);
  dst[0] = o0; dst[1] = o1;
}

extern "C" void kernel_launch(void* const* d_in, const int* in_sizes, int n_in,
                              void* d_out, int out_size, void* d_ws, size_t ws_size,
                              hipStream_t stream) {
  const float* x     = (const float*)d_in[0];
  const float* gateW = (const float*)d_in[1];
  const float* gateb = (const float*)d_in[2];
  const float* W1    = (const float*)d_in[3];
  const float* b1    = (const float*)d_in[4];
  const float* W2    = (const float*)d_in[5];
  const float* b2    = (const float*)d_in[6];
  float* out      = (float*)d_out;
  float* gate_out = out + (size_t)N_TOK * HD;

  char* ws = (char*)d_ws;
  size_t o = 0;
  u16* W1T = (u16*)(ws + o); o += (size_t)NE*HD*HD*2;   // 64 MiB
  u16* W2T = (u16*)(ws + o); o += (size_t)NE*HD*HD*2;   // 64 MiB
  u16* Xbf = (u16*)(ws + o);                            // 16.8 MiB (x as bf16)
  u16* Y   = Xbf;                       // Y aliases Xbf (Xbf dead after gemm1)
  o += (size_t)MAXROWS*HD*2;                            // 36 MiB region
  u16* Hbuf = (u16*)(ws + o); o += (size_t)MAXROWS*HD*2; // 36 MiB
  int*   meta   = (int*)(ws + o);   o += 8192;
  int*   picks  = (int*)(ws + o);   o += (size_t)N_TOK*2*4;
  float* wts    = (float*)(ws + o); o += (size_t)N_TOK*2*4;
  int*   slot   = (int*)(ws + o);   o += (size_t)N_TOK*2*4;
  int*   rowTok = (int*)(ws + o);   o += (size_t)MAXROWS*4;

  hipMemsetAsync(meta, 0, NCOPY*8*4, stream);
  hipMemsetAsync(rowTok, 0xFF, (size_t)MAXROWS*4, stream);

  convert_gate_kernel<<<dim3(NCVT1 + NGATE + NXCV), 256, 0, stream>>>(
      W1, W1T, x, gateW, gateb, gate_out, meta, picks, wts, Xbf);
  fill_kernel<<<(N_TOK*2)/256, 256, 0, stream>>>(picks, meta, slot, rowTok);
  gemm1_convw2_kernel<<<dim3(NWG + NCVT2), 512, 0, stream>>>(
      Xbf, W1T, b1, Hbuf, meta + 1024, rowTok, W2, W2T);
  moe_gemm_kernel<false, false><<<dim3(NWG), 512, 0, stream>>>(Hbuf, W2T, b2, Y,
                                                               meta + 1024, rowTok);
  combine_kernel<<<N_TOK, 256, 0, stream>>>(Y, slot, wts, out);
}

// Round 21
// 292.063 us; speedup vs baseline: 1.0147x; 1.0147x over previous
//
#include <hip/hip_runtime.h>
#include <hip/hip_bf16.h>

#define N_TOK 4096
#define HD    2048
#define NE    8

#define BM 128
#define BN 256
#define BK 32
#define NKS (HD/BK)                 /* 64 K-steps */
#define MAXROWS (N_TOK*2 + NE*BM)   /* 9216 */
#define TMAX (MAXROWS/BM)           /* 72 m-tiles */
#define NNT  (HD/BN)                /* 8 n-tiles */
#define NWG  (TMAX*NNT)             /* 576 blocks */
#define TSZ  ((BM+BN)*BK*2)         /* 24 KiB per K-tile buffer */

#define NCOPY 64                    /* privatized counter copies */
#define NCVT1 2048                  /* W1-convert-role blocks (256 thr kernel) */
#define NGATE (N_TOK/4)             /* 1024 gate-role blocks */
#define NXCV  (N_TOK*HD/2048)       /* 4096 x-convert-role blocks */
#define NCVT2 2048                  /* W2-convert-role blocks (in gemm1 launch) */

typedef __attribute__((ext_vector_type(4))) float f32x4;
typedef __attribute__((ext_vector_type(8))) short short8;
typedef __attribute__((ext_vector_type(8))) unsigned short ushort8;

typedef unsigned short u16;
typedef unsigned int   u32;

// meta int layout: [0..511] cnt[64][8]  [512..1023] cpfx[64][8]  [1024..1031] tot[8]

__device__ __forceinline__ float bf2f(u16 u) {
  union { u32 i; float f; } c; c.i = ((u32)u) << 16; return c.f;
}
__device__ __forceinline__ u16 f2bf(float f) {  // round-to-nearest-even
  u32 x = __float_as_uint(f);
  u32 r = (x + 0x7fffu + ((x >> 16) & 1u)) >> 16;
  return (u16)r;
}

__device__ __forceinline__ void gload_lds16(const void* gsrc, void* ldst) {
  __builtin_amdgcn_global_load_lds(
      (const __attribute__((address_space(1))) u32*)gsrc,
      (__attribute__((address_space(3))) u32*)ldst, 16, 0, 0);
}

// ---------------- fused: W1 convert+transpose (b<2048) || gate (2048..3071) ||
//                  x fp32->bf16 (3072..7167) — independent roles
// convert swizzle v5 (verified, 0 conflicts): slot XOR on (r>>3)&7.
__global__ __launch_bounds__(256) void convert_gate_kernel(
    const float* __restrict__ W1, u16* __restrict__ W1T,
    const float* __restrict__ x, const float* __restrict__ gW,
    const float* __restrict__ gb, float* __restrict__ gate_out,
    int* __restrict__ cnt, int* __restrict__ picks, float* __restrict__ wts,
    u16* __restrict__ Xbf) {
  __shared__ float smem[NE*HD];         // 64 KiB; convert & gate roles use it
  int b = blockIdx.x;
  int t = threadIdx.x;

  if (b >= NCVT1 + NGATE) {
    // ---- x-convert role: fp32 -> bf16, token order preserved (no LDS)
    size_t base = (size_t)(b - NCVT1 - NGATE) * 2048 + (size_t)t * 8;
    f32x4 a = *reinterpret_cast<const f32x4*>(x + base);
    f32x4 c = *reinterpret_cast<const f32x4*>(x + base + 4);
    ushort8 v;
    #pragma unroll
    for (int j = 0; j < 4; ++j) { v[j] = f2bf(a[j]); v[4+j] = f2bf(c[j]); }
    *reinterpret_cast<ushort8*>(Xbf + base) = v;
  } else if (b < NCVT1) {
    // ---- W1 convert role: W1[e][k][n] f32 -> W1T[e][n][k] bf16
    f32x4* tile4 = reinterpret_cast<f32x4*>(smem);
    int bx = b & 7, by = (b >> 3) & 31, e = b >> 8;   // 8 x 32 x 8
    size_t ebase = (size_t)e * HD * HD;
    int n0 = bx * 256;
    int k0 = by * 64;
    int l = t & 63, w = t >> 6;
    #pragma unroll
    for (int i = 0; i < 16; ++i) {
      int r = i*4 + w;
      f32x4 v = *reinterpret_cast<const f32x4*>(W1 + ebase + (size_t)(k0 + r) * HD + n0 + l*4);
      tile4[r*64 + (l ^ ((r >> 3) & 7))] = v;   // b128 write, minimal banks
    }
    __syncthreads();
    #pragma unroll
    for (int i = 0; i < 8; ++i) {
      int np = i*32 + (t >> 3);           // out row (n')
      int kc = (t & 7) * 8;               // out col base (k)
      int c4 = np >> 2, inner = np & 3;
      ushort8 v;
      #pragma unroll
      for (int j = 0; j < 8; ++j) {
        int k = kc + j;
        v[j] = f2bf(smem[(k*64 + (c4 ^ ((k >> 3) & 7)))*4 + inner]);  // 2-way
      }
      *reinterpret_cast<ushort8*>(W1T + ebase + (size_t)(n0 + np) * HD + k0 + kc) = v;
    }
  } else {
    // ---- gate role: gW staged in LDS; softmax -> top2 -> privatized atomics
    float* gwl = smem;                    // 64 KiB
    int gbk = b - NCVT1;                  // 0..1023
    {
      const f32x4* g4 = reinterpret_cast<const f32x4*>(gW);
      f32x4* l4 = reinterpret_cast<f32x4*>(gwl);
      #pragma unroll
      for (int i = 0; i < 16; ++i) l4[i*256 + t] = g4[i*256 + t];
    }
    __syncthreads();
    int wid = (gbk << 2) + (t >> 6);      // token
    int lane = t & 63;
    int copy = gbk & (NCOPY-1);
    const float* xr = x + (size_t)wid * HD;
    float s[NE] = {};
    for (int k = 0; k < HD; k += 256) {   // 8 iters, f32x4 per lane
      f32x4 xv = *reinterpret_cast<const f32x4*>(xr + k + lane*4);
      #pragma unroll
      for (int e = 0; e < NE; ++e) {
        f32x4 wv = *reinterpret_cast<const f32x4*>(&gwl[e*HD + k + lane*4]);
        s[e] += xv[0]*wv[0] + xv[1]*wv[1] + xv[2]*wv[2] + xv[3]*wv[3];
      }
    }
    #pragma unroll
    for (int e = 0; e < NE; ++e) {
      float v = s[e];
      #pragma unroll
      for (int off = 32; off > 0; off >>= 1) v += __shfl_xor(v, off);
      s[e] = v + gb[e];
    }
    float mx = s[0];
    #pragma unroll
    for (int e = 1; e < NE; ++e) mx = fmaxf(mx, s[e]);
    float sum = 0.f;
    #pragma unroll
    for (int e = 0; e < NE; ++e) { s[e] = expf(s[e] - mx); sum += s[e]; }
    float inv = 1.f / sum;
    #pragma unroll
    for (int e = 0; e < NE; ++e) s[e] *= inv;
    int e0 = 0; float v0 = s[0];
    #pragma unroll
    for (int e = 1; e < NE; ++e) if (s[e] > v0) { v0 = s[e]; e0 = e; }
    int e1 = -1; float v1 = -1.f;
    #pragma unroll
    for (int e = 0; e < NE; ++e) if (e != e0 && s[e] > v1) { v1 = s[e]; e1 = e; }
    if (lane == 0) {
      #pragma unroll
      for (int e = 0; e < NE; ++e) gate_out[(size_t)wid*NE + e] = s[e];
      int p0 = atomicAdd(&cnt[copy*8 + e0], 1);
      int p1 = atomicAdd(&cnt[copy*8 + e1], 1);
      picks[wid*2]   = (p0 << 9) | (copy << 3) | e0;
      picks[wid*2+1] = (p1 << 9) | (copy << 3) | e1;
      wts[wid*2]   = v0;
      wts[wid*2+1] = v1;
    }
  }
}

// ---------------- scan: copy-prefix per expert + totals
__global__ void scan_kernel(int* meta) {
  int e = threadIdx.x;
  if (e < NE) {
    int run = 0;
    for (int c = 0; c < NCOPY; ++c) {
      meta[512 + c*8 + e] = run;
      run += meta[c*8 + e];
    }
    meta[1024 + e] = run;
  }
}

// ---------------- fill: token picks -> padded row slots + row->token map
__global__ void fill_kernel(const int* __restrict__ picks, const int* __restrict__ meta,
                            int* __restrict__ slot, int* __restrict__ rowTok) {
  int i = blockIdx.x * 256 + threadIdx.x;
  if (i >= N_TOK*2) return;
  int p = picks[i];
  int e = p & 7, c = (p >> 3) & (NCOPY-1), pos = p >> 9;
  int base = 0;
  #pragma unroll
  for (int ee = 0; ee < NE; ++ee)
    if (ee < e) base += ((meta[1024+ee] + BM - 1) >> 7) << 7;
  int row = base + meta[512 + c*8 + e] + pos;
  slot[i] = row;
  rowTok[row] = i >> 1;
}

// ---------------- grouped GEMM core (512 thr, 128x256, BK=32, 3-buffer
// counted-vmcnt, 72 KiB LDS). IND: A rows via rowTok indirection.
__device__ __forceinline__ void compute_ktile(
    const char* ldsA, const char* ldsB, f32x4 (&acc)[4][4],
    int wr, int wc, int l15, int lhi) {
  short8 af[4], bfr[4];
  #pragma unroll
  for (int m = 0; m < 4; ++m) {
    int r = wr*64 + m*16 + l15;
    int c = lhi ^ ((r >> 1) & 3);       // swizzled read: worst 2-way (free)
    af[m] = *reinterpret_cast<const short8*>(ldsA + r*64 + c*16);
  }
  #pragma unroll
  for (int n = 0; n < 4; ++n) {
    int r = wc*64 + n*16 + l15;
    int c = lhi ^ ((r >> 1) & 3);
    bfr[n] = *reinterpret_cast<const short8*>(ldsB + r*64 + c*16);
  }
  #pragma unroll
  for (int m = 0; m < 4; ++m)
    #pragma unroll
    for (int n = 0; n < 4; ++n)
      acc[m][n] = __builtin_amdgcn_mfma_f32_16x16x32_bf16(af[m], bfr[n], acc[m][n], 0, 0, 0);
}

template<bool RELU, bool IND>
__device__ __forceinline__ void gemm_role(
    char* lds, int bid,
    const u16* __restrict__ A, const u16* __restrict__ WT,
    const float* __restrict__ bias, u16* __restrict__ Out,
    const int* __restrict__ tot, const int* __restrict__ rowTok) {
  // bijective XCD swizzle (m204): NWG % 8 == 0, chunk = NWG/8 = 72
  int wg = (bid & 7) * (NWG/8) + (bid >> 3);
  int t  = wg >> 3;          // m-tile index (0..71)
  int nt = wg & 7;           // n-tile index (0..7)
  // inline prefix over padded expert counts
  int tiles = 0, rows = 0, e = 0, tstart = 0, rbase = 0;
  #pragma unroll
  for (int i = 0; i < NE; ++i) {
    int tl = (tot[i] + BM - 1) >> 7;
    if (t >= tiles && t < tiles + tl) { e = i; tstart = tiles; rbase = rows; }
    tiles += tl; rows += tl << 7;
  }
  if (t >= tiles) return;
  int rowBase = rbase + (t - tstart) * BM;

  const u16* Bp = WT + ((size_t)e * HD + (size_t)nt * BN) * HD;

  int tid = threadIdx.x;
  int lane = tid & 63;
  int wv = tid >> 6;           // 0..7
  int wr = wv >> 2, wc = wv & 3;
  int l15 = lane & 15, lhi = lane >> 4;

  // hoisted per-thread staging sources (K-invariant row map)
  int aR = tid >> 2;
  int aC = (tid & 3) ^ ((aR >> 1) & 3);
  const u16* Asrc;
  if (IND) {
    int tk = rowTok[rowBase + aR];
    if (tk < 0) tk = 0;                  // pad row: finite garbage, never combined
    Asrc = A + (size_t)tk * HD + aC*8;
  } else {
    Asrc = A + (size_t)(rowBase + aR) * HD + aC*8;
  }
  int b1R = 128 + aR;
  int b1C = (tid & 3) ^ ((b1R >> 1) & 3);
  const u16* Bsrc0 = Bp + (size_t)aR * HD + aC*8;       // rows 0..127
  const u16* Bsrc1 = Bp + (size_t)b1R * HD + b1C*8;     // rows 128..255
  int ldsAoff = tid*16;
  int ldsB0off = BM*BK*2 + tid*16;
  int ldsB1off = BM*BK*2 + (512 + tid)*16;

  f32x4 acc[4][4] = {};

  // prologue: stage K-tiles 0 and 1
  gload_lds16(Asrc,       lds + ldsAoff);
  gload_lds16(Bsrc0,      lds + ldsB0off);
  gload_lds16(Bsrc1,      lds + ldsB1off);
  gload_lds16(Asrc  + BK, lds + TSZ + ldsAoff);
  gload_lds16(Bsrc0 + BK, lds + TSZ + ldsB0off);
  gload_lds16(Bsrc1 + BK, lds + TSZ + ldsB1off);

  int rd = 0;   // buffer holding K-tile ks (== ks % 3)
  for (int ks = 0; ks < NKS - 2; ++ks) {
    // own stage(ks) retired; stage(ks+1)'s 3 loads may stay in flight
    asm volatile("s_waitcnt vmcnt(3)" ::: "memory");
    // all waves: stage(ks) visible; all finished compute(ks-1)
    __builtin_amdgcn_s_barrier();
    int wi = rd + 2; if (wi >= 3) wi -= 3;
    // safe: buf[wi] last read at compute(ks-1), barrier-separated
    int koff = (ks+2)*BK;
    gload_lds16(Asrc  + koff, lds + wi*TSZ + ldsAoff);
    gload_lds16(Bsrc0 + koff, lds + wi*TSZ + ldsB0off);
    gload_lds16(Bsrc1 + koff, lds + wi*TSZ + ldsB1off);
    __builtin_amdgcn_sched_barrier(0);  // keep stage-issue before compute
    compute_ktile(lds + rd*TSZ, lds + rd*TSZ + BM*BK*2, acc, wr, wc, l15, lhi);
    if (++rd == 3) rd = 0;
  }
  // ks = NKS-2
  asm volatile("s_waitcnt vmcnt(3)" ::: "memory");
  __builtin_amdgcn_s_barrier();
  compute_ktile(lds + rd*TSZ, lds + rd*TSZ + BM*BK*2, acc, wr, wc, l15, lhi);
  if (++rd == 3) rd = 0;
  // ks = NKS-1: full drain
  asm volatile("s_waitcnt vmcnt(0)" ::: "memory");
  __builtin_amdgcn_s_barrier();
  compute_ktile(lds + rd*TSZ, lds + rd*TSZ + BM*BK*2, acc, wr, wc, l15, lhi);

  int orow = rowBase + wr*64;
  int ocol = nt*BN + wc*64;
  const float* bp = bias + (size_t)e * HD + ocol;
  #pragma unroll
  for (int n = 0; n < 4; ++n) {
    float bv = bp[n*16 + l15];
    #pragma unroll
    for (int m = 0; m < 4; ++m) {
      #pragma unroll
      for (int j = 0; j < 4; ++j) {
        float v = acc[m][n][j] + bv;
        if (RELU) v = fmaxf(v, 0.f);
        Out[(size_t)(orow + m*16 + lhi*4 + j) * HD + (ocol + n*16 + l15)] = f2bf(v);
      }
    }
  }
}

// ---------------- gemm1 fused with W2 convert role (independent blocks):
// blocks [0, NWG) run gemm1 (Xbf @ W1T -> Hbuf); blocks [NWG, NWG+NCVT2)
// convert W2 f32 -> W2T bf16 (consumed by the NEXT launch, gemm2).
__global__ __launch_bounds__(512, 4) void gemm1_convw2_kernel(
    const u16* __restrict__ A, const u16* __restrict__ WT,
    const float* __restrict__ bias, u16* __restrict__ Out,
    const int* __restrict__ tot, const int* __restrict__ rowTok,
    const float* __restrict__ W2, u16* __restrict__ W2T) {
  __shared__ char lds[3*TSZ];  // 72 KiB (convert role uses first 64 KiB)
  int bid = blockIdx.x;
  if (bid < NWG) {
    gemm_role<true, true>(lds, bid, A, WT, bias, Out, tot, rowTok);
  } else {
    // ---- W2 convert role, 512 threads: 64(k) x 256(n) tile, v5 swizzle
    float* smem = reinterpret_cast<float*>(lds);
    f32x4* tile4 = reinterpret_cast<f32x4*>(lds);
    int b2 = bid - NWG;                  // 0..2047
    int bx = b2 & 7, by = (b2 >> 3) & 31, e = b2 >> 8;  // 8 x 32 x 8
    size_t ebase = (size_t)e * HD * HD;
    int n0 = bx * 256;
    int k0 = by * 64;
    int t = threadIdx.x;
    int l = t & 63, w = t >> 6;          // w in 0..7
    #pragma unroll
    for (int i = 0; i < 8; ++i) {
      int r = i*8 + w;
      f32x4 v = *reinterpret_cast<const f32x4*>(W2 + ebase + (size_t)(k0 + r) * HD + n0 + l*4);
      tile4[r*64 + (l ^ ((r >> 3) & 7))] = v;
    }
    __syncthreads();
    #pragma unroll
    for (int i = 0; i < 4; ++i) {
      int np = i*64 + (t >> 3);           // out row (n'), 0..255
      int kc = (t & 7) * 8;               // out col base (k)
      int c4 = np >> 2, inner = np & 3;
      ushort8 v;
      #pragma unroll
      for (int j = 0; j < 8; ++j) {
        int k = kc + j;
        v[j] = f2bf(smem[(k*64 + (c4 ^ ((k >> 3) & 7)))*4 + inner]);
      }
      *reinterpret_cast<ushort8*>(W2T + ebase + (size_t)(n0 + np) * HD + k0 + kc) = v;
    }
  }
}

// ---------------- gemm2 (plain)
template<bool RELU, bool IND>
__global__ __launch_bounds__(512, 4) void moe_gemm_kernel(
    const u16* __restrict__ A, const u16* __restrict__ WT,
    const float* __restrict__ bias, u16* __restrict__ Out,
    const int* __restrict__ tot, const int* __restrict__ rowTok) {
  __shared__ char lds[3*TSZ];
  gemm_role<RELU, IND>(lds, blockIdx.x, A, WT, bias, Out, tot, rowTok);
}

// ---------------- combine: out[n] = w0*Y[slot0] + w1*Y[slot1]
__global__ __launch_bounds__(256) void combine_kernel(
    const u16* __restrict__ Y, const int* __restrict__ slot,
    const float* __restrict__ wts, float* __restrict__ out) {
  int n = blockIdx.x;
  int r0 = slot[n*2], r1 = slot[n*2+1];
  float w0 = wts[n*2], w1 = wts[n*2+1];
  int c = threadIdx.x * 8;
  ushort8 y0 = *reinterpret_cast<const ushort8*>(Y + (size_t)r0*HD + c);
  ushort8 y1 = *reinterpret_cast<const ushort8*>(Y + (size_t)r1*HD + c);
  f32x4 o0, o1;
  #pragma unroll
  for (int j = 0; j < 4; ++j) {
    o0[j] = w0*bf2f(y0[j])   + w1*bf2f(y1[j]);
    o1[j] = w0*bf2f(y0[4+j]) + w1*bf2f(y1[4+j]);
  }
  f32x4* dst = reinterpret_cast<f32x4*>(out + (size_t)n*HD + c);
  dst[0] = o0; dst[1] = o1;
}

extern "C" void kernel_launch(void* const* d_in, const int* in_sizes, int n_in,
                              void* d_out, int out_size, void* d_ws, size_t ws_size,
                              hipStream_t stream) {
  const float* x     = (const float*)d_in[0];
  const float* gateW = (const float*)d_in[1];
  const float* gateb = (const float*)d_in[2];
  const float* W1    = (const float*)d_in[3];
  const float* b1    = (const float*)d_in[4];
  const float* W2    = (const float*)d_in[5];
  const float* b2    = (const float*)d_in[6];
  float* out      = (float*)d_out;
  float* gate_out = out + (size_t)N_TOK * HD;

  char* ws = (char*)d_ws;
  size_t o = 0;
  u16* W1T = (u16*)(ws + o); o += (size_t)NE*HD*HD*2;   // 64 MiB
  u16* W2T = (u16*)(ws + o); o += (size_t)NE*HD*HD*2;   // 64 MiB
  u16* Xbf = (u16*)(ws + o);                            // 16.8 MiB (x as bf16)
  u16* Y   = Xbf;                       // Y aliases Xbf (Xbf dead after gemm1)
  o += (size_t)MAXROWS*HD*2;                            // 36 MiB region
  u16* Hbuf = (u16*)(ws + o); o += (size_t)MAXROWS*HD*2; // 36 MiB
  int*   meta   = (int*)(ws + o);   o += 8192;
  int*   picks  = (int*)(ws + o);   o += (size_t)N_TOK*2*4;
  float* wts    = (float*)(ws + o); o += (size_t)N_TOK*2*4;
  int*   slot   = (int*)(ws + o);   o += (size_t)N_TOK*2*4;
  int*   rowTok = (int*)(ws + o);   o += (size_t)MAXROWS*4;

  hipMemsetAsync(meta, 0, NCOPY*8*4, stream);
  hipMemsetAsync(rowTok, 0xFF, (size_t)MAXROWS*4, stream);

  convert_gate_kernel<<<dim3(NCVT1 + NGATE + NXCV), 256, 0, stream>>>(
      W1, W1T, x, gateW, gateb, gate_out, meta, picks, wts, Xbf);
  scan_kernel<<<1, 64, 0, stream>>>(meta);
  fill_kernel<<<(N_TOK*2)/256, 256, 0, stream>>>(picks, meta, slot, rowTok);
  gemm1_convw2_kernel<<<dim3(NWG + NCVT2), 512, 0, stream>>>(
      Xbf, W1T, b1, Hbuf, meta + 1024, rowTok, W2, W2T);
  moe_gemm_kernel<false, false><<<dim3(NWG), 512, 0, stream>>>(Hbuf, W2T, b2, Y,
                                                               meta + 1024, rowTok);
  combine_kernel<<<N_TOK, 256, 0, stream>>>(Y, slot, wts, out);
}